// Round 8
// baseline (8031.524 us; speedup 1.0000x reference)
//
#include <hip/hip_runtime.h>
#include <math.h>
#include <stdint.h>

#define BATCH 128
#define NF 49
#define EDIM 2048
#define EMBD 512
#define DDIM 512
#define VOC 12000
#define VOCP 12032
#define TT 21
#define G4 2048   // 4*D
#define UWN 2560  // 512 + 2048
#define NBLK 512  // persistent-kernel grid

typedef __bf16 bf16x8 __attribute__((ext_vector_type(8)));
typedef float f32x4 __attribute__((ext_vector_type(4)));
typedef unsigned short ushortx8 __attribute__((ext_vector_type(8)));
typedef unsigned short u16;

union U8 { ushortx8 u; bf16x8 b; };

__device__ __forceinline__ u16 bf16_rne(float x) {
    union { float f; unsigned u; } v; v.f = x;
    unsigned r = v.u + 0x7fffu + ((v.u >> 16) & 1u);
    return (u16)(r >> 16);
}
__device__ __forceinline__ float bf16_to_f(u16 h) {
    union { unsigned u; float f; } v; v.u = ((unsigned)h) << 16;
    return v.f;
}
__device__ __forceinline__ float sigmoidf(float x) { return 1.f / (1.f + expf(-x)); }

__device__ __forceinline__ void gload16(const void* g, void* l) {
    auto gp = reinterpret_cast<const __attribute__((address_space(1))) unsigned int*>(
        reinterpret_cast<uintptr_t>(g));
    auto lp = reinterpret_cast<__attribute__((address_space(3))) unsigned int*>(
        reinterpret_cast<uintptr_t>(l));
    __builtin_amdgcn_global_load_lds(gp, lp, 16, 0, 0);
}

// device-scope generation barrier (all NBLK blocks must be co-resident)
__device__ __forceinline__ void gbar(int* cnt, int* gen) {
    __threadfence();                    // release this block's stores (agent scope)
    __syncthreads();
    if (threadIdx.x == 0) {
        int g = __hip_atomic_load(gen, __ATOMIC_RELAXED, __HIP_MEMORY_SCOPE_AGENT);
        int a = __hip_atomic_fetch_add(cnt, 1, __ATOMIC_ACQ_REL, __HIP_MEMORY_SCOPE_AGENT);
        if (a == NBLK - 1) {
            __hip_atomic_store(cnt, 0, __ATOMIC_RELAXED, __HIP_MEMORY_SCOPE_AGENT);
            __hip_atomic_fetch_add(gen, 1, __ATOMIC_RELEASE, __HIP_MEMORY_SCOPE_AGENT);
        } else {
            while (__hip_atomic_load(gen, __ATOMIC_ACQUIRE, __HIP_MEMORY_SCOPE_AGENT) == g)
                __builtin_amdgcn_s_sleep(8);
        }
    }
    __syncthreads();
    __threadfence();                    // acquire: don't read stale caches
}

// =======================================================================
// pre-split bf16x3 GEMM (proven R6): C = A*W^T (+bias), hi/lo bf16 inputs
// =======================================================================
__global__ __launch_bounds__(256) void gemm_bf16s(
    const u16* __restrict__ Ahi, const u16* __restrict__ Alo, int lda,
    const u16* __restrict__ Whi, const u16* __restrict__ Wlo, int ldw,
    float* __restrict__ C, int ldc,
    const float* __restrict__ bias,
    int Nn, int K)
{
    __shared__ u16 Ah[128 * 32];
    __shared__ u16 Al[128 * 32];
    __shared__ u16 Wh[128 * 32];
    __shared__ u16 Wl[128 * 32];

    const int nbx = gridDim.x;
    const int nwg = nbx * gridDim.y;
    const int orig = blockIdx.y * nbx + blockIdx.x;
    const int q = nwg >> 3, r = nwg & 7;
    const int xcd = orig & 7, pos = orig >> 3;
    const int swz = (xcd < r ? xcd * (q + 1) : r * (q + 1) + (xcd - r) * q) + pos;
    const int by = swz / nbx, bx = swz - by * nbx;

    const int bm = by * 128;
    const int bn = bx * 128;
    const int tid = threadIdx.x;
    const int lane = tid & 63;
    const int wid = tid >> 6;
    const int wr = (wid >> 1) * 64;
    const int wc = (wid & 1) * 64;

    const int srow = wid * 32 + (lane >> 2);
    const int sslot = (lane & 3) ^ ((lane >> 2) & 3);
    const u16* a_src = Ahi + (size_t)(bm + srow) * lda + sslot * 8;
    const u16* al_src = Alo + (size_t)(bm + srow) * lda + sslot * 8;
    const u16* w_src = Whi + (size_t)(bn + srow) * ldw + sslot * 8;
    const u16* wl_src = Wlo + (size_t)(bn + srow) * ldw + sslot * 8;
    const int lds_base = (wid * 32) * 32;

    const int fr = lane & 15;
    const int ksl = lane >> 4;
    const int rsl = (ksl ^ (fr & 3)) * 8;

    f32x4 acc[4][4] = {};

    for (int k0 = 0; k0 < K; k0 += 32) {
        #pragma unroll
        for (int cch = 0; cch < 2; ++cch) {
            const size_t go = (size_t)cch * 16 * lda + k0;
            const size_t gw = (size_t)cch * 16 * ldw + k0;
            const int lo = lds_base + cch * 16 * 32;
            gload16(a_src + go, &Ah[lo]);
            gload16(al_src + go, &Al[lo]);
            gload16(w_src + gw, &Wh[lo]);
            gload16(wl_src + gw, &Wl[lo]);
        }
        __syncthreads();

        bf16x8 av_h[4], av_l[4], wv_h[4], wv_l[4];
        #pragma unroll
        for (int m = 0; m < 4; ++m) {
            int ar = wr + m * 16 + fr;
            av_h[m] = *(const bf16x8*)&Ah[ar * 32 + rsl];
            av_l[m] = *(const bf16x8*)&Al[ar * 32 + rsl];
        }
        #pragma unroll
        for (int n = 0; n < 4; ++n) {
            int wrw = wc + n * 16 + fr;
            wv_h[n] = *(const bf16x8*)&Wh[wrw * 32 + rsl];
            wv_l[n] = *(const bf16x8*)&Wl[wrw * 32 + rsl];
        }
        #pragma unroll
        for (int m = 0; m < 4; ++m)
            #pragma unroll
            for (int n = 0; n < 4; ++n) {
                acc[m][n] = __builtin_amdgcn_mfma_f32_16x16x32_bf16(av_h[m], wv_h[n], acc[m][n], 0, 0, 0);
                acc[m][n] = __builtin_amdgcn_mfma_f32_16x16x32_bf16(av_h[m], wv_l[n], acc[m][n], 0, 0, 0);
                acc[m][n] = __builtin_amdgcn_mfma_f32_16x16x32_bf16(av_l[m], wv_h[n], acc[m][n], 0, 0, 0);
            }
        __syncthreads();
    }

    #pragma unroll
    for (int n = 0; n < 4; ++n) {
        int col = bn + wc + n * 16 + (lane & 15);
        if (col >= Nn) continue;
        float bv = bias ? bias[col] : 0.f;
        #pragma unroll
        for (int m = 0; m < 4; ++m) {
            int row0 = bm + wr + m * 16 + (lane >> 4) * 4;
            #pragma unroll
            for (int rg = 0; rg < 4; ++rg)
                C[(size_t)(row0 + rg) * ldc + col] = acc[m][n][rg] + bv;
        }
    }
}

// =======================================================================
// small MFMA GEMM (M=128, init-only): one wave per 16x16 tile
// =======================================================================
__global__ __launch_bounds__(256) void small_mfma_gemm(
    const float* __restrict__ A, int lda,
    const u16* __restrict__ Whi,
    const u16* __restrict__ Wlo,
    int K,
    const float* __restrict__ bias,
    float* __restrict__ C, int ldc)
{
    const int tid = threadIdx.x;
    const int wave = tid >> 6;
    const int lane = tid & 63;
    const int g = blockIdx.x * 4 + wave;
    const int mt = g & 7;
    const int nt = g >> 3;
    const int fr = lane & 15;
    const int ksl = lane >> 4;

    const float* arow = A + (size_t)(mt * 16 + fr) * lda + ksl * 8;
    const u16* bhi = Whi + (size_t)(nt * 16 + fr) * K + ksl * 8;
    const u16* blo = Wlo + (size_t)(nt * 16 + fr) * K + ksl * 8;

    f32x4 acc = {};
    for (int k0 = 0; k0 < K; k0 += 32) {
        float4 f0 = *(const float4*)(arow + k0);
        float4 f1 = *(const float4*)(arow + k0 + 4);
        U8 ah, al;
        float fv[8] = {f0.x, f0.y, f0.z, f0.w, f1.x, f1.y, f1.z, f1.w};
        #pragma unroll
        for (int j = 0; j < 8; ++j) {
            u16 hh = bf16_rne(fv[j]);
            ah.u[j] = hh;
            al.u[j] = bf16_rne(fv[j] - bf16_to_f(hh));
        }
        U8 bh, bl;
        bh.u = *(const ushortx8*)(bhi + k0);
        bl.u = *(const ushortx8*)(blo + k0);
        acc = __builtin_amdgcn_mfma_f32_16x16x32_bf16(ah.b, bh.b, acc, 0, 0, 0);
        acc = __builtin_amdgcn_mfma_f32_16x16x32_bf16(ah.b, bl.b, acc, 0, 0, 0);
        acc = __builtin_amdgcn_mfma_f32_16x16x32_bf16(al.b, bh.b, acc, 0, 0, 0);
    }

    const int n = nt * 16 + (lane & 15);
    const int m0 = mt * 16 + (lane >> 4) * 4;
    const float bv = bias ? bias[n] : 0.f;
    #pragma unroll
    for (int rg = 0; rg < 4; ++rg)
        C[(size_t)(m0 + rg) * ldc + n] = acc[rg] + bv;
}

// =======================================================================
// helpers
// =======================================================================
__global__ __launch_bounds__(256) void split_mat_kernel(
    const float* __restrict__ src, int srcld, int cols, int rows, int rows_pad,
    u16* __restrict__ hi, u16* __restrict__ lo)
{
    int idx = blockIdx.x * 256 + threadIdx.x;
    if (idx >= rows_pad * cols) return;
    int r = idx / cols, k = idx - r * cols;
    float v = (r < rows) ? src[(size_t)r * srcld + k] : 0.f;
    u16 h = bf16_rne(v);
    hi[idx] = h;
    lo[idx] = bf16_rne(v - bf16_to_f(h));
}

__global__ __launch_bounds__(256) void uw_split_kernel(const float* __restrict__ Ua_w,
                                                       const float* __restrict__ Ua_b,
                                                       const float* __restrict__ W_hh,
                                                       u16* __restrict__ hi,
                                                       u16* __restrict__ lo,
                                                       float* __restrict__ biascat)
{
    int idx = blockIdx.x * 256 + threadIdx.x;
    if (idx < UWN * DDIM) {
        int n = idx >> 9, k = idx & 511;
        float v = (n < DDIM) ? Ua_w[n * DDIM + k] : W_hh[(size_t)(n - DDIM) * DDIM + k];
        u16 h = bf16_rne(v);
        hi[idx] = h;
        lo[idx] = bf16_rne(v - bf16_to_f(h));
    }
    if (idx < UWN)
        biascat[idx] = (idx < DDIM) ? Ua_b[idx] : 0.f;
}

__global__ __launch_bounds__(256) void mean_feat_kernel(const float* __restrict__ features,
                                                        float* __restrict__ mean_f)
{
    int idx = blockIdx.x * 256 + threadIdx.x;
    int b = idx >> 11, e = idx & 2047;
    float s = 0.f;
    for (int n = 0; n < NF; ++n)
        s += features[((size_t)(b * NF + n)) * EDIM + e];
    mean_f[idx] = s * (1.0f / NF);
}

__global__ __launch_bounds__(256) void gather_embed_split_kernel(const int* __restrict__ captions,
                                                                 const float* __restrict__ embedding,
                                                                 u16* __restrict__ ehi,
                                                                 u16* __restrict__ elo)
{
    int idx = blockIdx.x * 256 + threadIdx.x;
    int m = idx >> 9;
    int j = idx & 511;
    int b = m / TT, t = m - b * TT;
    int word = captions[b * (TT + 1) + t];
    float v = embedding[(size_t)word * EMBD + j];
    u16 h = bf16_rne(v);
    ehi[idx] = h;
    elo[idx] = bf16_rne(v - bf16_to_f(h));
}

__global__ __launch_bounds__(256) void bias_sum_kernel(const float* __restrict__ b_ih,
                                                       const float* __restrict__ b_hh,
                                                       float* __restrict__ bsum)
{
    int j = blockIdx.x * 256 + threadIdx.x;
    if (j < G4) bsum[j] = b_ih[j] + b_hh[j];
}

__global__ void reset_bar_kernel(int* bar) { bar[0] = 0; bar[1] = 0; }

// =======================================================================
// persistent kernel: entire 21-step recurrence, 512 blocks x 256 threads
// phase1: hp_g = h @ [Ua;W_hh]^T + biascat (MFMA, bf16x3, h pre-split)
// phase2: scores+softmax (per-b, x4 redundant) + gates + LSTM + h split
// =======================================================================
__global__ __launch_bounds__(256, 4) void decoder_loop_kernel(
    u16* __restrict__ h_hi, u16* __restrict__ h_lo,     // B x D (current)
    float* __restrict__ c,                              // B x D
    const u16* __restrict__ UW_hi, const u16* __restrict__ UW_lo,
    const float* __restrict__ biascat,                  // 2560
    float* __restrict__ hp_g,                           // B x 2560
    const float* __restrict__ f_proj,                   // (B*NF) x 512
    const float* __restrict__ Va_w, const float* __restrict__ Va_b,
    const float* __restrict__ F_ih,                     // (B*NF) x 2048
    const float* __restrict__ E_ih,                     // (B*T) x 2048
    u16* __restrict__ H_hi, u16* __restrict__ H_lo,     // (B*T) x D
    float* __restrict__ out_w,                          // B*T*NF
    int* __restrict__ bar)
{
    const int bid = blockIdx.x;
    const int tid = threadIdx.x;
    const int wid = tid >> 6;
    const int lane = tid & 63;
    const int fr = lane & 15;
    const int ksl = lane >> 4;

    __shared__ float s[64];
    __shared__ float comb[4][128];

    const int b  = bid >> 2;
    const int qd = bid & 3;
    const int jj = qd * 128 + (tid & 127);   // this thread's D-col
    const int nh = tid >> 7;                 // n-parity split

    for (int t = 0; t < TT; ++t) {
        if (t) gbar(bar, bar + 1);

        // ---------- phase 1: hp_g ----------
        {
            const int gid = bid * 4 + wid;   // 2048 waves, 1280 tiles
            if (gid < 1280) {
                const int mt = gid & 7, nt = gid >> 3;
                const u16* ah = h_hi + (size_t)(mt * 16 + fr) * DDIM + ksl * 8;
                const u16* al = h_lo + (size_t)(mt * 16 + fr) * DDIM + ksl * 8;
                const u16* bh = UW_hi + (size_t)(nt * 16 + fr) * DDIM + ksl * 8;
                const u16* bl = UW_lo + (size_t)(nt * 16 + fr) * DDIM + ksl * 8;
                f32x4 acc = {};
                #pragma unroll 4
                for (int k0 = 0; k0 < DDIM; k0 += 32) {
                    U8 avh, avl, bvh, bvl;
                    avh.u = *(const ushortx8*)(ah + k0);
                    avl.u = *(const ushortx8*)(al + k0);
                    bvh.u = *(const ushortx8*)(bh + k0);
                    bvl.u = *(const ushortx8*)(bl + k0);
                    acc = __builtin_amdgcn_mfma_f32_16x16x32_bf16(avh.b, bvh.b, acc, 0, 0, 0);
                    acc = __builtin_amdgcn_mfma_f32_16x16x32_bf16(avh.b, bvl.b, acc, 0, 0, 0);
                    acc = __builtin_amdgcn_mfma_f32_16x16x32_bf16(avl.b, bvh.b, acc, 0, 0, 0);
                }
                const int n = nt * 16 + fr;
                const int m0 = mt * 16 + ksl * 4;
                const float bv = biascat[n];
                #pragma unroll
                for (int rg = 0; rg < 4; ++rg)
                    hp_g[(size_t)(m0 + rg) * UWN + n] = acc[rg] + bv;
            }
        }
        gbar(bar, bar + 1);

        // ---------- phase 2 ----------
        const float* hp = hp_g + (size_t)b * UWN;
        for (int n = wid; n < NF; n += 4) {
            const float* fp = f_proj + ((size_t)(b * NF + n)) * DDIM;
            float sum = 0.f;
            for (int d = lane; d < DDIM; d += 64)
                sum += Va_w[d] * tanhf(fp[d] + hp[d]);
            for (int off = 32; off; off >>= 1) sum += __shfl_down(sum, off);
            if (lane == 0) s[n] = sum + Va_b[0];
        }
        __syncthreads();
        if (tid < 64) {
            float v = (lane < NF) ? s[lane] : -1e30f;
            float mx = v;
            for (int off = 32; off; off >>= 1) mx = fmaxf(mx, __shfl_xor(mx, off));
            float e = (lane < NF) ? expf(v - mx) : 0.f;
            float sm = e;
            for (int off = 32; off; off >>= 1) sm += __shfl_xor(sm, off);
            float p = e / sm;
            s[lane] = (lane < NF) ? p : 0.f;
            if (qd == 0 && lane < NF)
                out_w[((size_t)b * TT + t) * NF + lane] = p;
        }
        __syncthreads();
        {
            const float* eih = E_ih + ((size_t)b * TT + t) * G4 + jj;
            const float* fib = F_ih + (size_t)b * NF * G4 + jj;
            float a0, a1, a2, a3;
            if (nh == 0) {
                a0 = hp[DDIM + jj]            + eih[0];
                a1 = hp[DDIM + jj + DDIM]     + eih[DDIM];
                a2 = hp[DDIM + jj + 2 * DDIM] + eih[2 * DDIM];
                a3 = hp[DDIM + jj + 3 * DDIM] + eih[3 * DDIM];
            } else { a0 = a1 = a2 = a3 = 0.f; }
            for (int n = nh; n < NF; n += 2) {
                float w = s[n];
                const float* fp = fib + (size_t)n * G4;
                a0 += w * fp[0];
                a1 += w * fp[DDIM];
                a2 += w * fp[2 * DDIM];
                a3 += w * fp[3 * DDIM];
            }
            if (nh == 1) {
                comb[0][tid & 127] = a0; comb[1][tid & 127] = a1;
                comb[2][tid & 127] = a2; comb[3][tid & 127] = a3;
            }
            __syncthreads();
            if (nh == 0) {
                a0 += comb[0][tid]; a1 += comb[1][tid];
                a2 += comb[2][tid]; a3 += comb[3][tid];
                float iv = sigmoidf(a0), fv = sigmoidf(a1);
                float gv = tanhf(a2),  ov = sigmoidf(a3);
                int idx = b * DDIM + jj;
                float c2 = fv * c[idx] + iv * gv;
                float h2 = ov * tanhf(c2);
                c[idx] = c2;
                u16 hh = bf16_rne(h2);
                u16 hl = bf16_rne(h2 - bf16_to_f(hh));
                h_hi[idx] = hh; h_lo[idx] = hl;
                size_t hix = ((size_t)b * TT + t) * DDIM + jj;
                H_hi[hix] = hh; H_lo[hix] = hl;
            }
        }
        // LDS reuse + h visibility protected by loop-top gbar
    }
}

// =======================================================================
// host side
// =======================================================================
static void launch_gemm_s(hipStream_t stream,
                          const u16* Ahi, const u16* Alo, int lda,
                          const u16* Whi, const u16* Wlo, int ldw,
                          float* C, int ldc, const float* bias,
                          int M, int Nn, int K)
{
    dim3 grid((Nn + 127) / 128, M / 128);
    hipLaunchKernelGGL(gemm_bf16s, grid, dim3(256), 0, stream,
                       Ahi, Alo, lda, Whi, Wlo, ldw, C, ldc, bias, Nn, K);
}

static void launch_split(hipStream_t stream, const float* src, int srcld, int cols,
                         int rows, int rows_pad, u16* hi, u16* lo)
{
    int total = rows_pad * cols;
    hipLaunchKernelGGL(split_mat_kernel, dim3((total + 255) / 256), dim3(256), 0, stream,
                       src, srcld, cols, rows, rows_pad, hi, lo);
}

extern "C" void kernel_launch(void* const* d_in, const int* in_sizes, int n_in,
                              void* d_out, int out_size, void* d_ws, size_t ws_size,
                              hipStream_t stream)
{
    const float* features = (const float*)d_in[0];
    const int*   captions = (const int*)d_in[1];
    const float* embedding= (const float*)d_in[2];
    const float* Wa_w = (const float*)d_in[3];
    const float* Wa_b = (const float*)d_in[4];
    const float* Ua_w = (const float*)d_in[5];
    const float* Ua_b = (const float*)d_in[6];
    const float* Va_w = (const float*)d_in[7];
    const float* Va_b = (const float*)d_in[8];
    const float* W_ih = (const float*)d_in[9];
    const float* W_hh = (const float*)d_in[10];
    const float* b_ih = (const float*)d_in[11];
    const float* b_hh = (const float*)d_in[12];
    const float* ih_w = (const float*)d_in[13];
    const float* ih_b = (const float*)d_in[14];
    const float* ic_w = (const float*)d_in[15];
    const float* ic_b = (const float*)d_in[16];
    const float* fc_w = (const float*)d_in[17];
    const float* fc_b = (const float*)d_in[18];

    float* out_w = (float*)d_out;
    float* out_p = out_w + (size_t)BATCH * TT * NF;

    float* ws = (float*)d_ws;
    size_t off = 0;
    auto alloc = [&](size_t n) { float* p = ws + off; off += n; return p; };

    float* f_proj  = alloc(3211264);
    float* F_ih    = alloc(12845056);
    float* E_ih    = alloc(5505024);
    float* hp_g    = alloc(327680);
    float* mean_f  = alloc(262144);   // after init, reused as h_hi/h_lo
    float* h0f     = alloc(65536);
    float* c       = alloc(65536);
    float* bsum    = alloc(4096);     // [0,2048) bsum; +3072: barrier ints
    float* biascat = alloc(4096);
    u16* feat_hi = (u16*)alloc(6422528);
    u16* feat_lo = (u16*)alloc(6422528);
    u16* emb_hi  = (u16*)alloc(688128);
    u16* emb_lo  = (u16*)alloc(688128);
    u16* H_hi    = (u16*)alloc(688128);
    u16* H_lo    = (u16*)alloc(688128);
    u16* Wa_hi   = (u16*)alloc(524288);
    u16* Wa_lo   = (u16*)alloc(524288);
    u16* Wf_hi   = (u16*)alloc(2097152);
    u16* Wf_lo   = (u16*)alloc(2097152);
    u16* We_hi   = (u16*)alloc(524288);
    u16* We_lo   = (u16*)alloc(524288);
    u16* UW_hi   = (u16*)alloc(655360);
    u16* UW_lo   = (u16*)alloc(655360);
    u16* fcw_hi  = (u16*)alloc(3080192);
    u16* fcw_lo  = (u16*)alloc(3080192);

    u16* h_hi = (u16*)mean_f;                 // overlay (mean_f dead after init)
    u16* h_lo = (u16*)(mean_f + 32768);
    int* bar  = (int*)(bsum + 3072);
    // temp ih/ic split overlays the fc split area (stream-ordered before fc split)
    u16* T_hi = fcw_hi;
    u16* T_lo = fcw_lo;

    // ---- init ----
    hipLaunchKernelGGL(mean_feat_kernel, dim3(BATCH * EDIM / 256), dim3(256), 0, stream,
                       features, mean_f);
    launch_split(stream, ih_w, EDIM, EDIM, DDIM, DDIM, T_hi, T_lo);
    hipLaunchKernelGGL(small_mfma_gemm, dim3(DDIM / 8), dim3(256), 0, stream,
                       mean_f, EDIM, T_hi, T_lo, EDIM, ih_b, h0f, DDIM);
    launch_split(stream, ic_w, EDIM, EDIM, DDIM, DDIM, T_hi, T_lo);
    hipLaunchKernelGGL(small_mfma_gemm, dim3(DDIM / 8), dim3(256), 0, stream,
                       mean_f, EDIM, T_hi, T_lo, EDIM, ic_b, c, DDIM);
    // mean_f dead from here; h0 -> h_hi/h_lo (overlay)
    launch_split(stream, h0f, DDIM, DDIM, BATCH, BATCH, h_hi, h_lo);
    // fc split area now free
    launch_split(stream, fc_w, DDIM, DDIM, VOC, VOCP, fcw_hi, fcw_lo);

    launch_split(stream, features, EDIM, EDIM, BATCH * NF, BATCH * NF, feat_hi, feat_lo);
    launch_split(stream, Wa_w, EDIM, EDIM, DDIM, DDIM, Wa_hi, Wa_lo);
    launch_split(stream, W_ih, EDIM + EMBD, EDIM, G4, G4, Wf_hi, Wf_lo);
    launch_split(stream, W_ih + EDIM, EDIM + EMBD, EMBD, G4, G4, We_hi, We_lo);
    hipLaunchKernelGGL(gather_embed_split_kernel, dim3(BATCH * TT * EMBD / 256), dim3(256), 0, stream,
                       captions, embedding, emb_hi, emb_lo);
    hipLaunchKernelGGL(bias_sum_kernel, dim3((G4 + 255) / 256), dim3(256), 0, stream,
                       b_ih, b_hh, bsum);
    hipLaunchKernelGGL(uw_split_kernel, dim3((UWN * DDIM + 255) / 256), dim3(256), 0, stream,
                       Ua_w, Ua_b, W_hh, UW_hi, UW_lo, biascat);
    hipLaunchKernelGGL(reset_bar_kernel, dim3(1), dim3(1), 0, stream, bar);

    // ---- big GEMMs ----
    launch_gemm_s(stream, feat_hi, feat_lo, EDIM, Wa_hi, Wa_lo, EDIM,
                  f_proj, DDIM, Wa_b, BATCH * NF, DDIM, EDIM);
    launch_gemm_s(stream, feat_hi, feat_lo, EDIM, Wf_hi, Wf_lo, EDIM,
                  F_ih, G4, nullptr, BATCH * NF, G4, EDIM);
    launch_gemm_s(stream, emb_hi, emb_lo, EMBD, We_hi, We_lo, EMBD,
                  E_ih, G4, bsum, BATCH * TT, G4, EMBD);

    // ---- whole recurrence: ONE persistent kernel ----
    hipLaunchKernelGGL(decoder_loop_kernel, dim3(NBLK), dim3(256), 0, stream,
                       h_hi, h_lo, c, UW_hi, UW_lo, biascat, hp_g,
                       f_proj, Va_w, Va_b, F_ih, E_ih, H_hi, H_lo, out_w, bar);

    // ---- preds ----
    launch_gemm_s(stream, H_hi, H_lo, DDIM, fcw_hi, fcw_lo, DDIM,
                  out_p, VOC, fc_b, BATCH * TT, VOC, DDIM);
}

// Round 9
// 2011.558 us; speedup vs baseline: 3.9927x; 3.9927x over previous
//
#include <hip/hip_runtime.h>
#include <math.h>
#include <stdint.h>

#define BATCH 128
#define NF 49
#define EDIM 2048
#define EMBD 512
#define DDIM 512
#define VOC 12000
#define VOCP 12032
#define TT 21
#define G4 2048   // 4*D
#define UWN 2560  // 512 + 2048

typedef __bf16 bf16x8 __attribute__((ext_vector_type(8)));
typedef float f32x4 __attribute__((ext_vector_type(4)));
typedef unsigned short ushortx8 __attribute__((ext_vector_type(8)));
typedef unsigned short u16;

union U8 { ushortx8 u; bf16x8 b; };

__device__ __forceinline__ u16 bf16_rne(float x) {
    union { float f; unsigned u; } v; v.f = x;
    unsigned r = v.u + 0x7fffu + ((v.u >> 16) & 1u);
    return (u16)(r >> 16);
}
__device__ __forceinline__ float bf16_to_f(u16 h) {
    union { unsigned u; float f; } v; v.u = ((unsigned)h) << 16;
    return v.f;
}
__device__ __forceinline__ float sigmoidf(float x) { return 1.f / (1.f + expf(-x)); }

__device__ __forceinline__ void gload16(const void* g, void* l) {
    auto gp = reinterpret_cast<const __attribute__((address_space(1))) unsigned int*>(
        reinterpret_cast<uintptr_t>(g));
    auto lp = reinterpret_cast<__attribute__((address_space(3))) unsigned int*>(
        reinterpret_cast<uintptr_t>(l));
    __builtin_amdgcn_global_load_lds(gp, lp, 16, 0, 0);
}

// =======================================================================
// pre-split bf16x3 GEMM (proven R6): C = A*W^T (+bias), hi/lo bf16 inputs
// =======================================================================
__global__ __launch_bounds__(256) void gemm_bf16s(
    const u16* __restrict__ Ahi, const u16* __restrict__ Alo, int lda,
    const u16* __restrict__ Whi, const u16* __restrict__ Wlo, int ldw,
    float* __restrict__ C, int ldc,
    const float* __restrict__ bias,
    int Nn, int K)
{
    __shared__ u16 Ah[128 * 32];
    __shared__ u16 Al[128 * 32];
    __shared__ u16 Wh[128 * 32];
    __shared__ u16 Wl[128 * 32];

    const int nbx = gridDim.x;
    const int nwg = nbx * gridDim.y;
    const int orig = blockIdx.y * nbx + blockIdx.x;
    const int q = nwg >> 3, r = nwg & 7;
    const int xcd = orig & 7, pos = orig >> 3;
    const int swz = (xcd < r ? xcd * (q + 1) : r * (q + 1) + (xcd - r) * q) + pos;
    const int by = swz / nbx, bx = swz - by * nbx;

    const int bm = by * 128;
    const int bn = bx * 128;
    const int tid = threadIdx.x;
    const int lane = tid & 63;
    const int wid = tid >> 6;
    const int wr = (wid >> 1) * 64;
    const int wc = (wid & 1) * 64;

    const int srow = wid * 32 + (lane >> 2);
    const int sslot = (lane & 3) ^ ((lane >> 2) & 3);
    const u16* a_src = Ahi + (size_t)(bm + srow) * lda + sslot * 8;
    const u16* al_src = Alo + (size_t)(bm + srow) * lda + sslot * 8;
    const u16* w_src = Whi + (size_t)(bn + srow) * ldw + sslot * 8;
    const u16* wl_src = Wlo + (size_t)(bn + srow) * ldw + sslot * 8;
    const int lds_base = (wid * 32) * 32;

    const int fr = lane & 15;
    const int ksl = lane >> 4;
    const int rsl = (ksl ^ (fr & 3)) * 8;

    f32x4 acc[4][4] = {};

    for (int k0 = 0; k0 < K; k0 += 32) {
        #pragma unroll
        for (int cch = 0; cch < 2; ++cch) {
            const size_t go = (size_t)cch * 16 * lda + k0;
            const size_t gw = (size_t)cch * 16 * ldw + k0;
            const int lo = lds_base + cch * 16 * 32;
            gload16(a_src + go, &Ah[lo]);
            gload16(al_src + go, &Al[lo]);
            gload16(w_src + gw, &Wh[lo]);
            gload16(wl_src + gw, &Wl[lo]);
        }
        __syncthreads();

        bf16x8 av_h[4], av_l[4], wv_h[4], wv_l[4];
        #pragma unroll
        for (int m = 0; m < 4; ++m) {
            int ar = wr + m * 16 + fr;
            av_h[m] = *(const bf16x8*)&Ah[ar * 32 + rsl];
            av_l[m] = *(const bf16x8*)&Al[ar * 32 + rsl];
        }
        #pragma unroll
        for (int n = 0; n < 4; ++n) {
            int wrw = wc + n * 16 + fr;
            wv_h[n] = *(const bf16x8*)&Wh[wrw * 32 + rsl];
            wv_l[n] = *(const bf16x8*)&Wl[wrw * 32 + rsl];
        }
        #pragma unroll
        for (int m = 0; m < 4; ++m)
            #pragma unroll
            for (int n = 0; n < 4; ++n) {
                acc[m][n] = __builtin_amdgcn_mfma_f32_16x16x32_bf16(av_h[m], wv_h[n], acc[m][n], 0, 0, 0);
                acc[m][n] = __builtin_amdgcn_mfma_f32_16x16x32_bf16(av_h[m], wv_l[n], acc[m][n], 0, 0, 0);
                acc[m][n] = __builtin_amdgcn_mfma_f32_16x16x32_bf16(av_l[m], wv_h[n], acc[m][n], 0, 0, 0);
            }
        __syncthreads();
    }

    #pragma unroll
    for (int n = 0; n < 4; ++n) {
        int col = bn + wc + n * 16 + (lane & 15);
        if (col >= Nn) continue;
        float bv = bias ? bias[col] : 0.f;
        #pragma unroll
        for (int m = 0; m < 4; ++m) {
            int row0 = bm + wr + m * 16 + (lane >> 4) * 4;
            #pragma unroll
            for (int rg = 0; rg < 4; ++rg)
                C[(size_t)(row0 + rg) * ldc + col] = acc[m][n][rg] + bv;
        }
    }
}

// =======================================================================
// small MFMA GEMM (M=128): one wave per 16x16 tile
// =======================================================================
__global__ __launch_bounds__(256) void small_mfma_gemm(
    const float* __restrict__ A, int lda,
    const u16* __restrict__ Whi,
    const u16* __restrict__ Wlo,
    int K,
    const float* __restrict__ bias,
    float* __restrict__ C, int ldc)
{
    const int tid = threadIdx.x;
    const int wave = tid >> 6;
    const int lane = tid & 63;
    const int g = blockIdx.x * 4 + wave;
    const int mt = g & 7;
    const int nt = g >> 3;
    const int fr = lane & 15;
    const int ksl = lane >> 4;

    const float* arow = A + (size_t)(mt * 16 + fr) * lda + ksl * 8;
    const u16* bhi = Whi + (size_t)(nt * 16 + fr) * K + ksl * 8;
    const u16* blo = Wlo + (size_t)(nt * 16 + fr) * K + ksl * 8;

    f32x4 acc = {};
    for (int k0 = 0; k0 < K; k0 += 32) {
        float4 f0 = *(const float4*)(arow + k0);
        float4 f1 = *(const float4*)(arow + k0 + 4);
        U8 ah, al;
        float fv[8] = {f0.x, f0.y, f0.z, f0.w, f1.x, f1.y, f1.z, f1.w};
        #pragma unroll
        for (int j = 0; j < 8; ++j) {
            u16 hh = bf16_rne(fv[j]);
            ah.u[j] = hh;
            al.u[j] = bf16_rne(fv[j] - bf16_to_f(hh));
        }
        U8 bh, bl;
        bh.u = *(const ushortx8*)(bhi + k0);
        bl.u = *(const ushortx8*)(blo + k0);
        acc = __builtin_amdgcn_mfma_f32_16x16x32_bf16(ah.b, bh.b, acc, 0, 0, 0);
        acc = __builtin_amdgcn_mfma_f32_16x16x32_bf16(ah.b, bl.b, acc, 0, 0, 0);
        acc = __builtin_amdgcn_mfma_f32_16x16x32_bf16(al.b, bh.b, acc, 0, 0, 0);
    }

    const int n = nt * 16 + (lane & 15);
    const int m0 = mt * 16 + (lane >> 4) * 4;
    const float bv = bias ? bias[n] : 0.f;
    #pragma unroll
    for (int rg = 0; rg < 4; ++rg)
        C[(size_t)(m0 + rg) * ldc + n] = acc[rg] + bv;
}

// =======================================================================
// helpers
// =======================================================================
__global__ __launch_bounds__(256) void split_mat_kernel(
    const float* __restrict__ src, int srcld, int cols, int rows, int rows_pad,
    u16* __restrict__ hi, u16* __restrict__ lo)
{
    int idx = blockIdx.x * 256 + threadIdx.x;
    if (idx >= rows_pad * cols) return;
    int r = idx / cols, k = idx - r * cols;
    float v = (r < rows) ? src[(size_t)r * srcld + k] : 0.f;
    u16 h = bf16_rne(v);
    hi[idx] = h;
    lo[idx] = bf16_rne(v - bf16_to_f(h));
}

__global__ __launch_bounds__(256) void uw_split_kernel(const float* __restrict__ Ua_w,
                                                       const float* __restrict__ Ua_b,
                                                       const float* __restrict__ W_hh,
                                                       u16* __restrict__ hi,
                                                       u16* __restrict__ lo,
                                                       float* __restrict__ biascat)
{
    int idx = blockIdx.x * 256 + threadIdx.x;
    if (idx < UWN * DDIM) {
        int n = idx >> 9, k = idx & 511;
        float v = (n < DDIM) ? Ua_w[n * DDIM + k] : W_hh[(size_t)(n - DDIM) * DDIM + k];
        u16 h = bf16_rne(v);
        hi[idx] = h;
        lo[idx] = bf16_rne(v - bf16_to_f(h));
    }
    if (idx < UWN)
        biascat[idx] = (idx < DDIM) ? Ua_b[idx] : 0.f;
}

__global__ __launch_bounds__(256) void mean_feat_kernel(const float* __restrict__ features,
                                                        float* __restrict__ mean_f)
{
    int idx = blockIdx.x * 256 + threadIdx.x;
    int b = idx >> 11, e = idx & 2047;
    float s = 0.f;
    for (int n = 0; n < NF; ++n)
        s += features[((size_t)(b * NF + n)) * EDIM + e];
    mean_f[idx] = s * (1.0f / NF);
}

__global__ __launch_bounds__(256) void gather_embed_split_kernel(const int* __restrict__ captions,
                                                                 const float* __restrict__ embedding,
                                                                 u16* __restrict__ ehi,
                                                                 u16* __restrict__ elo)
{
    int idx = blockIdx.x * 256 + threadIdx.x;
    int m = idx >> 9;
    int j = idx & 511;
    int b = m / TT, t = m - b * TT;
    int word = captions[b * (TT + 1) + t];
    float v = embedding[(size_t)word * EMBD + j];
    u16 h = bf16_rne(v);
    ehi[idx] = h;
    elo[idx] = bf16_rne(v - bf16_to_f(h));
}

__global__ __launch_bounds__(256) void bias_sum_kernel(const float* __restrict__ b_ih,
                                                       const float* __restrict__ b_hh,
                                                       float* __restrict__ bsum)
{
    int j = blockIdx.x * 256 + threadIdx.x;
    if (j < G4) bsum[j] = b_ih[j] + b_hh[j];
}

// =======================================================================
// fused per-step v2: scores+softmax + gates (float4 streams) + LSTM
// grid = 256 blocks (b, d-half), 256 threads (4 waves)
// gates: q = tid>>6 picks gate segment, each thread streams ONE contiguous
// float4 per n from F_ih (49 independent loads) -> BW-bound, not latency.
// =======================================================================
__global__ __launch_bounds__(256) void fused_step2_kernel(
    const float* __restrict__ f_proj,   // (B*NF) x 512
    const float* __restrict__ hp_g,     // B x 2560: [h_proj | hh-gates]
    const float* __restrict__ Va_w,
    const float* __restrict__ Va_b,
    const float* __restrict__ F_ih,     // (B*NF) x 2048
    const float* __restrict__ E_ih,     // (B*T) x 2048 (incl b_ih+b_hh)
    float* __restrict__ h,              // B x D (f32, for next hp GEMM)
    float* __restrict__ c,              // B x D
    u16* __restrict__ H_hi, u16* __restrict__ H_lo,  // (B*T) x D
    float* __restrict__ out_w,
    int t)
{
    const int b  = blockIdx.x >> 1;
    const int dh = blockIdx.x & 1;      // d-half: covers d in [dh*256, dh*256+256)
    const int tid = threadIdx.x;
    const int wave = tid >> 6;
    const int lane = tid & 63;
    __shared__ float s[64];
    __shared__ float gs[4][256];        // [gate q][local d]

    // ---- scores + softmax (redundant per d-half; f_proj read 2x/step) ----
    const float* hp = hp_g + (size_t)b * UWN;
    for (int n = wave; n < NF; n += 4) {
        const float* fp = f_proj + ((size_t)(b * NF + n)) * DDIM;
        float sum = 0.f;
        for (int d = lane; d < DDIM; d += 64)
            sum += Va_w[d] * tanhf(fp[d] + hp[d]);
        for (int off = 32; off; off >>= 1) sum += __shfl_down(sum, off);
        if (lane == 0) s[n] = sum + Va_b[0];
    }
    __syncthreads();
    if (tid < 64) {
        float v = (lane < NF) ? s[lane] : -1e30f;
        float mx = v;
        for (int off = 32; off; off >>= 1) mx = fmaxf(mx, __shfl_xor(mx, off));
        float e = (lane < NF) ? expf(v - mx) : 0.f;
        float sm = e;
        for (int off = 32; off; off >>= 1) sm += __shfl_xor(sm, off);
        float p = e / sm;
        s[lane] = (lane < NF) ? p : 0.f;
        if (dh == 0 && lane < NF)
            out_w[((size_t)b * TT + t) * NF + lane] = p;
    }
    __syncthreads();

    // ---- gates: thread -> (q, 4 consecutive d) ----
    const int q  = tid >> 6;                 // 0..3
    const int dl = (tid & 63) * 4;           // local d 0..252
    const int gcol = q * DDIM + dh * 256 + dl;   // col in G4
    const float* eih = E_ih + ((size_t)b * TT + t) * G4;

    float4 a = *(const float4*)(hp + DDIM + gcol);
    {
        float4 e4 = *(const float4*)(eih + gcol);
        a.x += e4.x; a.y += e4.y; a.z += e4.z; a.w += e4.w;
    }
    const float* fib = F_ih + (size_t)b * NF * G4 + gcol;
    #pragma unroll 7
    for (int n = 0; n < NF; ++n) {
        float w = s[n];
        float4 f4 = *(const float4*)(fib + (size_t)n * G4);
        a.x += w * f4.x; a.y += w * f4.y; a.z += w * f4.z; a.w += w * f4.w;
    }
    *(float4*)&gs[q][dl] = a;
    __syncthreads();

    // ---- LSTM cell: 64 threads x 4 d each ----
    if (tid < 64) {
        const int dl0 = tid * 4;
        const int d   = dh * 256 + dl0;
        const int idx = b * DDIM + d;
        float4 iv4 = *(const float4*)&gs[0][dl0];
        float4 fv4 = *(const float4*)&gs[1][dl0];
        float4 gv4 = *(const float4*)&gs[2][dl0];
        float4 ov4 = *(const float4*)&gs[3][dl0];
        float4 cold = *(const float4*)(c + idx);
        float4 cnew, hnew;
        float ci[4] = {cold.x, cold.y, cold.z, cold.w};
        float ii[4] = {iv4.x, iv4.y, iv4.z, iv4.w};
        float ff[4] = {fv4.x, fv4.y, fv4.z, fv4.w};
        float gg[4] = {gv4.x, gv4.y, gv4.z, gv4.w};
        float oo[4] = {ov4.x, ov4.y, ov4.z, ov4.w};
        float co[4], ho[4];
        u16 hh4[4], hl4[4];
        #pragma unroll
        for (int k = 0; k < 4; ++k) {
            float iv = sigmoidf(ii[k]);
            float fv = sigmoidf(ff[k]);
            float gv = tanhf(gg[k]);
            float ov = sigmoidf(oo[k]);
            float c2 = fv * ci[k] + iv * gv;
            float h2 = ov * tanhf(c2);
            co[k] = c2; ho[k] = h2;
            hh4[k] = bf16_rne(h2);
            hl4[k] = bf16_rne(h2 - bf16_to_f(hh4[k]));
        }
        cnew = make_float4(co[0], co[1], co[2], co[3]);
        hnew = make_float4(ho[0], ho[1], ho[2], ho[3]);
        *(float4*)(c + idx) = cnew;
        *(float4*)(h + idx) = hnew;
        size_t hix = ((size_t)b * TT + t) * DDIM + d;
        ushort4 hh = make_ushort4(hh4[0], hh4[1], hh4[2], hh4[3]);
        ushort4 hl = make_ushort4(hl4[0], hl4[1], hl4[2], hl4[3]);
        *(ushort4*)(H_hi + hix) = hh;
        *(ushort4*)(H_lo + hix) = hl;
    }
}

// =======================================================================
// host side
// =======================================================================
static void launch_gemm_s(hipStream_t stream,
                          const u16* Ahi, const u16* Alo, int lda,
                          const u16* Whi, const u16* Wlo, int ldw,
                          float* C, int ldc, const float* bias,
                          int M, int Nn, int K)
{
    dim3 grid((Nn + 127) / 128, M / 128);
    hipLaunchKernelGGL(gemm_bf16s, grid, dim3(256), 0, stream,
                       Ahi, Alo, lda, Whi, Wlo, ldw, C, ldc, bias, Nn, K);
}

static void launch_split(hipStream_t stream, const float* src, int srcld, int cols,
                         int rows, int rows_pad, u16* hi, u16* lo)
{
    int total = rows_pad * cols;
    hipLaunchKernelGGL(split_mat_kernel, dim3((total + 255) / 256), dim3(256), 0, stream,
                       src, srcld, cols, rows, rows_pad, hi, lo);
}

extern "C" void kernel_launch(void* const* d_in, const int* in_sizes, int n_in,
                              void* d_out, int out_size, void* d_ws, size_t ws_size,
                              hipStream_t stream)
{
    const float* features = (const float*)d_in[0];
    const int*   captions = (const int*)d_in[1];
    const float* embedding= (const float*)d_in[2];
    const float* Wa_w = (const float*)d_in[3];
    const float* Wa_b = (const float*)d_in[4];
    const float* Ua_w = (const float*)d_in[5];
    const float* Ua_b = (const float*)d_in[6];
    const float* Va_w = (const float*)d_in[7];
    const float* Va_b = (const float*)d_in[8];
    const float* W_ih = (const float*)d_in[9];
    const float* W_hh = (const float*)d_in[10];
    const float* b_ih = (const float*)d_in[11];
    const float* b_hh = (const float*)d_in[12];
    const float* ih_w = (const float*)d_in[13];
    const float* ih_b = (const float*)d_in[14];
    const float* ic_w = (const float*)d_in[15];
    const float* ic_b = (const float*)d_in[16];
    const float* fc_w = (const float*)d_in[17];
    const float* fc_b = (const float*)d_in[18];

    float* out_w = (float*)d_out;
    float* out_p = out_w + (size_t)BATCH * TT * NF;

    float* ws = (float*)d_ws;
    size_t off = 0;
    auto alloc = [&](size_t n) { float* p = ws + off; off += n; return p; };

    float* f_proj  = alloc(3211264);
    float* F_ih    = alloc(12845056);
    float* E_ih    = alloc(5505024);
    float* hp_g    = alloc(327680);
    float* mean_f  = alloc(262144);
    float* h       = alloc(65536);
    float* c       = alloc(65536);
    float* bsum    = alloc(4096);
    float* biascat = alloc(4096);
    u16* feat_hi = (u16*)alloc(6422528);
    u16* feat_lo = (u16*)alloc(6422528);
    u16* emb_hi  = (u16*)alloc(688128);
    u16* emb_lo  = (u16*)alloc(688128);
    u16* H_hi    = (u16*)alloc(688128);
    u16* H_lo    = (u16*)alloc(688128);
    u16* Wa_hi   = (u16*)alloc(524288);
    u16* Wa_lo   = (u16*)alloc(524288);
    u16* Wf_hi   = (u16*)alloc(2097152);
    u16* Wf_lo   = (u16*)alloc(2097152);
    u16* We_hi   = (u16*)alloc(524288);
    u16* We_lo   = (u16*)alloc(524288);
    u16* UW_hi   = (u16*)alloc(655360);
    u16* UW_lo   = (u16*)alloc(655360);
    u16* fcw_hi  = (u16*)alloc(3080192);
    u16* fcw_lo  = (u16*)alloc(3080192);

    // temp ih/ic split overlays the fc split area (stream-ordered before fc split)
    u16* T_hi = fcw_hi;
    u16* T_lo = fcw_lo;

    // ---- init ----
    hipLaunchKernelGGL(mean_feat_kernel, dim3(BATCH * EDIM / 256), dim3(256), 0, stream,
                       features, mean_f);
    launch_split(stream, ih_w, EDIM, EDIM, DDIM, DDIM, T_hi, T_lo);
    hipLaunchKernelGGL(small_mfma_gemm, dim3(DDIM / 8), dim3(256), 0, stream,
                       mean_f, EDIM, T_hi, T_lo, EDIM, ih_b, h, DDIM);
    launch_split(stream, ic_w, EDIM, EDIM, DDIM, DDIM, T_hi, T_lo);
    hipLaunchKernelGGL(small_mfma_gemm, dim3(DDIM / 8), dim3(256), 0, stream,
                       mean_f, EDIM, T_hi, T_lo, EDIM, ic_b, c, DDIM);
    // fc split area now free
    launch_split(stream, fc_w, DDIM, DDIM, VOC, VOCP, fcw_hi, fcw_lo);

    launch_split(stream, features, EDIM, EDIM, BATCH * NF, BATCH * NF, feat_hi, feat_lo);
    launch_split(stream, Wa_w, EDIM, EDIM, DDIM, DDIM, Wa_hi, Wa_lo);
    launch_split(stream, W_ih, EDIM + EMBD, EDIM, G4, G4, Wf_hi, Wf_lo);
    launch_split(stream, W_ih + EDIM, EDIM + EMBD, EMBD, G4, G4, We_hi, We_lo);
    hipLaunchKernelGGL(gather_embed_split_kernel, dim3(BATCH * TT * EMBD / 256), dim3(256), 0, stream,
                       captions, embedding, emb_hi, emb_lo);
    hipLaunchKernelGGL(bias_sum_kernel, dim3((G4 + 255) / 256), dim3(256), 0, stream,
                       b_ih, b_hh, bsum);
    hipLaunchKernelGGL(uw_split_kernel, dim3((UWN * DDIM + 255) / 256), dim3(256), 0, stream,
                       Ua_w, Ua_b, W_hh, UW_hi, UW_lo, biascat);

    // ---- big GEMMs (pre-split bf16x3, gload_lds) ----
    launch_gemm_s(stream, feat_hi, feat_lo, EDIM, Wa_hi, Wa_lo, EDIM,
                  f_proj, DDIM, Wa_b, BATCH * NF, DDIM, EDIM);
    launch_gemm_s(stream, feat_hi, feat_lo, EDIM, Wf_hi, Wf_lo, EDIM,
                  F_ih, G4, nullptr, BATCH * NF, G4, EDIM);
    launch_gemm_s(stream, emb_hi, emb_lo, EMBD, We_hi, We_lo, EMBD,
                  E_ih, G4, bsum, BATCH * TT, G4, EMBD);

    // ---- sequential loop: 2 launches/step ----
    for (int t = 0; t < TT; ++t) {
        hipLaunchKernelGGL(small_mfma_gemm, dim3(UWN / 8), dim3(256), 0, stream,
                           h, DDIM, UW_hi, UW_lo, DDIM, biascat, hp_g, UWN);
        hipLaunchKernelGGL(fused_step2_kernel, dim3(BATCH * 2), dim3(256), 0, stream,
                           f_proj, hp_g, Va_w, Va_b, F_ih, E_ih, h, c,
                           H_hi, H_lo, out_w, t);
    }

    // ---- preds ----
    launch_gemm_s(stream, H_hi, H_lo, DDIM, fcw_hi, fcw_lo, DDIM,
                  out_p, VOC, fc_b, BATCH * TT, VOC, DDIM);
}